// Round 11
// baseline (107.108 us; speedup 1.0000x reference)
//
#include <hip/hip_runtime.h>
#include <math.h>

#define BB 4096
#define CC 1024        // padded class count (1000 real + 24 pad)
#define DD 256

typedef __attribute__((ext_vector_type(4))) float f32x4;
typedef __attribute__((ext_vector_type(2))) float f32x2;
typedef __bf16 bf16x8 __attribute__((ext_vector_type(8)));

// ---- workspace byte offsets ----
#define AHI_B   (size_t)0                      // [1024][256] bf16 class rows (512 KB)
#define YHI_B   (size_t)524288                 // [2][4096][256] bf16 (4 MB)
#define RS0_B   (size_t)4718592                // [1024] float4: x2, xn, (1+x2)/xn, psi
#define YS_B    (size_t)4734976                // [2][4096] float2: y2, laby
#define PART_B  (size_t)4800512                // [2][32][1024] float4: S,T,PP (1 MB)
#define CNTF_B  (size_t)5849088                // float[1024] class multiplicity
#define ACC_B   (size_t)5853184                // double[2]
#define CNT_B   (size_t)5853200                // int: completion counter

#define CLIPV 0.99999f
#define LOG_EPS_C (-11.512925464970229f)   // ln(1e-5)
#define LN2F 0.6931471805599453f
#define PIF 3.14159265358979323846f
#define NBLK (32 * 8 * 2)                  // fused grid size

__device__ __forceinline__ void gload16(const void* g, void* l) {
    __builtin_amdgcn_global_load_lds((const __attribute__((address_space(1))) void*)g,
                                     (__attribute__((address_space(3))) void*)l, 16, 0, 0);
}

__device__ __forceinline__ unsigned short f2bf(float f) {
    unsigned u = __float_as_uint(f);
    u += 0x7fffu + ((u >> 16) & 1u);
    return (unsigned short)(u >> 16);
}

__device__ __forceinline__ f32x2 splat2(float s) { return (f32x2){s, s}; }
__device__ __forceinline__ f32x2 emax2(f32x2 a, f32x2 b) { return __builtin_elementwise_max(a, b); }
__device__ __forceinline__ f32x2 emin2(f32x2 a, f32x2 b) { return __builtin_elementwise_min(a, b); }

// 16-lane-row sum reduction via DPP row rotates (pure VALU; no LDS pipe)
#define DPP_ROR_ADD(v, ctrl) \
    v += __builtin_bit_cast(float, __builtin_amdgcn_update_dpp( \
        0, __builtin_bit_cast(int, v), (ctrl), 0xf, 0xf, true))
__device__ __forceinline__ float rowsum16(float v) {
    DPP_ROR_ADD(v, 0x121);   // row_ror:1
    DPP_ROR_ADD(v, 0x122);   // row_ror:2
    DPP_ROR_ADD(v, 0x124);   // row_ror:4
    DPP_ROR_ADD(v, 0x128);   // row_ror:8
    return v;
}

// ONE prep kernel, 1D grid of 2304 blocks:
//  bid <  256 : 4 classes/block — bf16 rows, row stats, atomics-free hist via LDS label scan
//  bid >= 256 : y prep (2 pairs x 1024 blocks x 4 rows)
// block 0 additionally zeroes accum + completion counter.
__global__ void prep_kernel(const float* __restrict__ yimg, const float* __restrict__ ytxt,
                            const float* __restrict__ cw, const int* __restrict__ labels,
                            char* __restrict__ ws, double* __restrict__ accum,
                            int* __restrict__ cnt) {
    const int bid = blockIdx.x;
    const int tid = threadIdx.x;
    const int t = tid & 63;
    if (bid < 256) {
        __shared__ int labL[4096];
        #pragma unroll
        for (int i = 0; i < 4; ++i)
            ((int4*)labL)[tid + i * 256] = ((const int4*)labels)[tid + i * 256];
        if (bid == 0 && tid == 0) { accum[0] = 0.0; accum[1] = 0.0; *cnt = 0; }
        __syncthreads();
        int c = bid * 4 + (tid >> 6);
        int srcc = (c < 1000) ? c : 0;             // pad rows reuse class 0 (weight 0)
        float4 v = ((const float4*)(cw + (size_t)srcc * DD))[t];
        ushort4 h;
        h.x = f2bf(v.x); h.y = f2bf(v.y); h.z = f2bf(v.z); h.w = f2bf(v.w);
        ((ushort4*)(ws + AHI_B + (size_t)c * 512))[t] = h;
        float sq = v.x*v.x + v.y*v.y + v.z*v.z + v.w*v.w;
        #pragma unroll
        for (int off = 32; off > 0; off >>= 1) sq += __shfl_down(sq, off);
        // atomics-free class count: 64 lanes scan 64 labels each
        int cn = 0;
        #pragma unroll 8
        for (int i = t; i < 4096; i += 64) cn += (labL[i] == c) ? 1 : 0;
        #pragma unroll
        for (int off = 32; off > 0; off >>= 1) cn += __shfl_down(cn, off);
        if (t == 0) {
            float xn = sqrtf(sq);
            float invxn = 1.0f / xn;
            float a = 0.1f * (1.f - sq) * invxn;
            a = fminf(fmaxf(a, -CLIPV), CLIPV);
            float psi = asinf(a);
            ((float4*)(ws + RS0_B))[c] = make_float4(sq, xn, invxn + xn, psi);
            ((float*)(ws + CNTF_B))[c] = (float)cn;
        }
    } else {
        int k = bid - 256;                         // 0..2047
        int pair = k >> 10;
        int row = (k & 1023) * 4 + (tid >> 6);
        const float* Y = pair ? ytxt : yimg;
        float4 v = ((const float4*)(Y + (size_t)row * DD))[t];
        ushort4 h;
        h.x = f2bf(v.x); h.y = f2bf(v.y); h.z = f2bf(v.z); h.w = f2bf(v.w);
        ((ushort4*)(ws + YHI_B + (size_t)pair * 2097152 + (size_t)row * 512))[t] = h;
        float sq = v.x*v.x + v.y*v.y + v.z*v.z + v.w*v.w;
        #pragma unroll
        for (int off = 32; off > 0; off >>= 1) sq += __shfl_down(sq, off);
        if (t == 0)
            ((float2*)(ws + YS_B))[(size_t)pair * BB + row] = make_float2(sq, __int_as_float(labels[row]));
    }
}

// 128x128 tile over [class(1024) x y(4096)], 512 threads (8 waves, 4x2),
// K-chunk 64 double-buffered, k-group-major LDS, packed-f32 elementwise,
// DPP reductions, class-multiplicity weights. LAST BLOCK does merge+finalize.
__launch_bounds__(512, 3)
__global__ void fused_kernel(char* __restrict__ ws, double* __restrict__ accum,
                             int* __restrict__ cnt, float* __restrict__ out) {
    __shared__ unsigned short AhL[2][8192], BhL[2][8192];  // 16 KB per buf
    __shared__ float4 rs0l[128];
    __shared__ float2 ysl[128];
    __shared__ float  cntl[128];
    __shared__ float  smrg[128][8];
    __shared__ float  sAtom[8];
    __shared__ double dAtom[8];
    __shared__ int    lastFlag;

    const int tid = threadIdx.x;
    const int l = tid & 63;
    const int w = tid >> 6;                 // 0..7
    const int wm = w >> 1, wn = w & 1;      // 4x2 wave grid; 32x64 per wave
    const int bx = blockIdx.x, by = blockIdx.y, pair = blockIdx.z;
    const int rowbase = by * 128, colbase = bx * 128;

    const char* srcA = ws + AHI_B + ((size_t)(rowbase + (w & 1) * 64 + l)) * 512 + (w >> 1) * 16;
    const char* srcB = ws + YHI_B + (size_t)pair * 2097152
                     + ((size_t)(colbase + (w & 1) * 64 + l)) * 512 + (w >> 1) * 16;
    const unsigned wboff = (unsigned)((w >> 1) * 2048 + (w & 1) * 1024);  // wave-uniform

    if (tid < 128) {
        rs0l[tid] = ((const float4*)(ws + RS0_B))[rowbase + tid];
    } else if (tid < 256) {
        ysl[tid - 128] = ((const float2*)(ws + YS_B))[(size_t)pair * BB + (tid - 128) + colbase];
    } else if (tid < 384) {
        cntl[tid - 256] = ((const float*)(ws + CNTF_B))[rowbase + (tid - 256)];
    }

    f32x4 acc[2][4];
    #pragma unroll
    for (int i = 0; i < 2; ++i)
        #pragma unroll
        for (int j = 0; j < 4; ++j) acc[i][j] = (f32x4){0.f, 0.f, 0.f, 0.f};

    // ---- prologue: stage chunk 0 into buf 0 ----
    gload16(srcA,      (char*)AhL[0] + wboff);
    gload16(srcA + 64, (char*)AhL[0] + wboff + 8192);
    gload16(srcB,      (char*)BhL[0] + wboff);
    gload16(srcB + 64, (char*)BhL[0] + wboff + 8192);
    asm volatile("s_waitcnt vmcnt(0)" ::: "memory");
    __syncthreads();

    #pragma unroll
    for (int c = 0; c < 4; ++c) {
        const int nb = (c + 1) & 1, cb = c & 1;
        if (c < 3) {                               // prefetch next chunk (overlaps MFMA)
            gload16(srcA + (c + 1) * 128,      (char*)AhL[nb] + wboff);
            gload16(srcA + (c + 1) * 128 + 64, (char*)AhL[nb] + wboff + 8192);
            gload16(srcB + (c + 1) * 128,      (char*)BhL[nb] + wboff);
            gload16(srcB + (c + 1) * 128 + 64, (char*)BhL[nb] + wboff + 8192);
        }
        #pragma unroll
        for (int ks = 0; ks < 2; ++ks) {
            const int kgl = ks * 4 + (l >> 4);
            const int abyte = (kgl * 128 + wm * 32 + (l & 15)) * 16;
            const int bbyte = (kgl * 128 + wn * 64 + (l & 15)) * 16;
            bf16x8 ah[2], bh[4];
            #pragma unroll
            for (int mi = 0; mi < 2; ++mi)
                ah[mi] = *(const bf16x8*)((const char*)AhL[cb] + abyte + mi * 256);
            #pragma unroll
            for (int ni = 0; ni < 4; ++ni)
                bh[ni] = *(const bf16x8*)((const char*)BhL[cb] + bbyte + ni * 256);
            #pragma unroll
            for (int mi = 0; mi < 2; ++mi)
                #pragma unroll
                for (int ni = 0; ni < 4; ++ni)
                    acc[mi][ni] = __builtin_amdgcn_mfma_f32_16x16x32_bf16(ah[mi], bh[ni], acc[mi][ni], 0, 0, 0);
        }
        if (c < 3) {
            asm volatile("s_waitcnt vmcnt(0)" ::: "memory");
            __syncthreads();
        }
    }

    // ---- elementwise (packed f32 pairs over ni), class rows weighted by cnt ----
    f32x2 entl2 = splat2(0.f);
    f32x2 y2p[2], opy2p[2];
    int labyc[4];
    #pragma unroll
    for (int p = 0; p < 2; ++p) {
        float2 a = ysl[wn * 64 + (p * 2 + 0) * 16 + (l & 15)];
        float2 b = ysl[wn * 64 + (p * 2 + 1) * 16 + (l & 15)];
        y2p[p] = (f32x2){a.x, b.x};
        opy2p[p] = (f32x2){1.f + a.x, 1.f + b.x};
        labyc[p * 2 + 0] = __float_as_int(a.y);
        labyc[p * 2 + 1] = __float_as_int(b.y);
    }
    #pragma unroll
    for (int mi = 0; mi < 2; ++mi) {
        #pragma unroll
        for (int rr = 0; rr < 4; ++rr) {
            int rl_ = wm * 32 + mi * 16 + (l >> 4) * 4 + rr;
            int cls = rowbase + rl_;
            float4 r0 = rs0l[rl_];
            float cntw = cntl[rl_];
            float x2 = r0.x, xn = r0.y, opx2i = r0.z, psi = r0.w;
            f32x2 x2py2[2], x2y2p1[2], xnopy2[2];
            #pragma unroll
            for (int p = 0; p < 2; ++p) {
                x2py2[p]  = y2p[p] + x2;
                x2y2p1[p] = y2p[p] * x2 + 1.f;
                xnopy2[p] = opy2p[p] * xn;
            }
            f32x2 S2 = splat2(0.f), T2 = splat2(0.f), PP2 = splat2(0.f), rowE = splat2(0.f);
            #pragma unroll
            for (int p = 0; p < 2; ++p) {
                bool pos0 = (cls == labyc[p * 2 + 0]);
                bool pos1 = (cls == labyc[p * 2 + 1]);
                f32x2 dotv = (f32x2){acc[mi][p * 2 + 0][rr], acc[mi][p * 2 + 1][rr]};
                f32x2 m2dot = dotv * -2.f;
                f32x2 d2 = x2py2[p] + m2dot;                    // ||x-y||^2
                f32x2 q2 = x2y2p1[p] + m2dot;                   // mobius denom
                f32x2 t = emax2(d2 * q2, splat2(1e-30f));
                f32x2 rs = (f32x2){__builtin_amdgcn_rsqf(t[0]), __builtin_amdgcn_rsqf(t[1])};
                f32x2 s_ = t * rs;                              // sqrt(q2*d2)
                // --- entailment E ---
                f32x2 numer = dotv * opx2i - xnopy2[p];
                f32x2 arg = numer * rs;
                f32x2 ax = emin2(__builtin_elementwise_abs(arg), splat2(CLIPV));
                f32x2 pl = ax * -0.0012624911f + 0.0066700901f;
                pl = pl * ax + -0.0170881256f;
                pl = pl * ax +  0.0308918810f;
                pl = pl * ax + -0.0501743046f;
                pl = pl * ax +  0.0889789874f;
                pl = pl * ax + -0.2145988016f;
                pl = pl * ax +  1.5707963050f;
                f32x2 om = 1.f - ax;
                f32x2 sq = (f32x2){sqrtf(om[0]), sqrtf(om[1])};
                f32x2 racos = sq * pl;
                f32x2 pmr = PIF - racos;
                f32x2 theta;
                theta[0] = (arg[0] < 0.f) ? pmr[0] : racos[0];
                theta[1] = (arg[1] < 0.f) ? pmr[1] : racos[1];
                f32x2 h = theta - psi;
                f32x2 g = emax2(h, splat2(0.f));
                f32x2 nc = emax2(1.f - g, splat2(0.f));
                f32x2 contrib;
                contrib[0] = pos0 ? g[0] : nc[0];
                contrib[1] = pos1 ? g[1] : nc[1];
                rowE += contrib;
                // --- dist + softmax: e = exp(-dist) = (q2e-s)/(q2e+s) ---
                f32x2 q2e = q2 + 1e-5f;
                f32x2 ne = q2e - s_;
                f32x2 de = q2e + s_;
                f32x2 rd = (f32x2){__builtin_amdgcn_rcpf(de[0]), __builtin_amdgcn_rcpf(de[1])};
                f32x2 e_ = ne * rd;
                f32x2 lu = (f32x2){__builtin_amdgcn_logf(e_[0]), __builtin_amdgcn_logf(e_[1])};
                f32x2 nd = lu * LN2F;                           // -dist
                S2 += e_;
                T2 = e_ * nd + T2;
                f32x2 pe;
                pe[0] = pos0 ? e_[0] : 0.f;
                pe[1] = pos1 ? e_[1] : 0.f;
                PP2 += pe;
            }
            entl2 = rowE * splat2(cntw) + entl2;    // weight by class multiplicity
            float S = rowsum16(S2[0] + S2[1]);
            float T = rowsum16(T2[0] + T2[1]);
            float PP = rowsum16(PP2[0] + PP2[1]);
            if ((l & 15) == 0) {
                smrg[rl_][wn * 4 + 0] = S; smrg[rl_][wn * 4 + 1] = T; smrg[rl_][wn * 4 + 2] = PP;
            }
        }
    }
    __syncthreads();
    if (tid < 128) {
        float4 o;
        o.x = smrg[tid][0] + smrg[tid][4];
        o.y = smrg[tid][1] + smrg[tid][5];
        o.z = smrg[tid][2] + smrg[tid][6];
        o.w = 0.f;
        ((float4*)(ws + PART_B))[((size_t)pair * 32 + bx) * CC + rowbase + tid] = o;
    }
    float entl = entl2[0] + entl2[1];
    #pragma unroll
    for (int off = 32; off > 0; off >>= 1) entl += __shfl_xor(entl, off);
    if (l == 0) sAtom[w] = entl;
    __syncthreads();
    if (tid == 0) {
        float tot = 0.f;
        #pragma unroll
        for (int i = 0; i < 8; ++i) tot += sAtom[i];
        atomicAdd(&accum[0], (double)tot);
    }

    // ---- last-block merge + finalize ----
    __threadfence();                       // all threads: make PART stores + atomics visible
    __syncthreads();
    if (tid == 0) lastFlag = (atomicAdd(cnt, 1) == NBLK - 1) ? 1 : 0;
    __syncthreads();
    if (!lastFlag) return;

    const float* cntf = (const float*)(ws + CNTF_B);
    double hv = 0.0;
    for (int k = tid; k < 2 * CC; k += 512) {
        int pr = k >> 10, c = k & (CC - 1);
        const float4* part = (const float4*)(ws + PART_B) + (size_t)pr * 32 * CC + c;
        float S = 0.f, T = 0.f, PP = 0.f;
        #pragma unroll 4
        for (int cb = 0; cb < 32; ++cb) {
            float4 v = part[(size_t)cb * CC];
            S += v.x; T += v.y; PP += v.z;
        }
        float wgt = cntf[c];
        float logc = logf(1.0f / wgt + 1e-5f);     // inf for wgt==0, guarded below
        float invS = 1.f / S;
        float fp = PP * invS;
        float rl = T * invS - logf(S) - fp * logc - (1.f - fp) * LOG_EPS_C;
        hv += (wgt > 0.f) ? (double)(rl * wgt) : 0.0;
    }
    #pragma unroll
    for (int off = 32; off > 0; off >>= 1) hv += __shfl_down(hv, off);
    if (l == 0) dAtom[w] = hv;
    __syncthreads();
    if (tid == 0) {
        double hsum = 0.0;
        #pragma unroll
        for (int i = 0; i < 8; ++i) hsum += dAtom[i];
        double esum = atomicAdd(&accum[0], 0.0);   // coherent cross-XCD read
        float e = (float)esum;
        float h = (float)(hsum * (1.0 / 4096.0));
        out[0] = e;
        out[1] = h;
        out[2] = e + h;
    }
}

extern "C" void kernel_launch(void* const* d_in, const int* in_sizes, int n_in,
                              void* d_out, int out_size, void* d_ws, size_t ws_size,
                              hipStream_t stream) {
    (void)in_sizes; (void)n_in; (void)out_size; (void)ws_size;
    const float* img = (const float*)d_in[0];
    const float* txt = (const float*)d_in[1];
    const float* cw  = (const float*)d_in[2];
    const int* labels = (const int*)d_in[3];
    float* out = (float*)d_out;
    char* wsb = (char*)d_ws;
    double* accum = (double*)(wsb + ACC_B);
    int* cnt = (int*)(wsb + CNT_B);

    prep_kernel<<<2304, 256, 0, stream>>>(img, txt, cw, labels, wsb, accum, cnt);
    fused_kernel<<<dim3(32, 8, 2), 512, 0, stream>>>(wsb, accum, cnt, out);
}

// Round 12
// 44.717 us; speedup vs baseline: 2.3953x; 2.3953x over previous
//
#include <hip/hip_runtime.h>
#include <math.h>

#define BB 4096
#define CC 1024        // padded class count (1000 real + 24 pad)
#define DD 256

typedef __attribute__((ext_vector_type(4))) float f32x4;
typedef __attribute__((ext_vector_type(2))) float f32x2;
typedef __bf16 bf16x8 __attribute__((ext_vector_type(8)));

// ---- workspace byte offsets ----
#define AHI_B   (size_t)0                      // [1024][256] bf16 class rows (512 KB)
#define YHI_B   (size_t)524288                 // [2][4096][256] bf16 (4 MB)
#define RS0_B   (size_t)4718592                // [1024] float4: x2, xn, (1+x2)/xn, psi
#define YS_B    (size_t)4734976                // [2][4096] float2: y2, laby
#define PART_B  (size_t)4800512                // [2][32][1024] float4: S,T,PP (1 MB)
#define CNTF_B  (size_t)5849088                // float[1024] class multiplicity
#define ACC_B   (size_t)5853184                // double[2]
#define CNT_B   (size_t)5853200                // int: merge completion counter

#define CLIPV 0.99999f
#define LOG_EPS_C (-11.512925464970229f)   // ln(1e-5)
#define LN2F 0.6931471805599453f
#define PIF 3.14159265358979323846f

__device__ __forceinline__ void gload16(const void* g, void* l) {
    __builtin_amdgcn_global_load_lds((const __attribute__((address_space(1))) void*)g,
                                     (__attribute__((address_space(3))) void*)l, 16, 0, 0);
}

__device__ __forceinline__ unsigned short f2bf(float f) {
    unsigned u = __float_as_uint(f);
    u += 0x7fffu + ((u >> 16) & 1u);
    return (unsigned short)(u >> 16);
}

__device__ __forceinline__ f32x2 splat2(float s) { return (f32x2){s, s}; }
__device__ __forceinline__ f32x2 emax2(f32x2 a, f32x2 b) { return __builtin_elementwise_max(a, b); }
__device__ __forceinline__ f32x2 emin2(f32x2 a, f32x2 b) { return __builtin_elementwise_min(a, b); }

// 16-lane-row sum reduction via DPP row rotates (pure VALU; no LDS pipe)
#define DPP_ROR_ADD(v, ctrl) \
    v += __builtin_bit_cast(float, __builtin_amdgcn_update_dpp( \
        0, __builtin_bit_cast(int, v), (ctrl), 0xf, 0xf, true))
__device__ __forceinline__ float rowsum16(float v) {
    DPP_ROR_ADD(v, 0x121);   // row_ror:1
    DPP_ROR_ADD(v, 0x122);   // row_ror:2
    DPP_ROR_ADD(v, 0x124);   // row_ror:4
    DPP_ROR_ADD(v, 0x128);   // row_ror:8
    return v;
}

// ONE prep kernel, 1D grid of 2304 blocks:
//  bid <  256 : 4 classes/block — bf16 rows, row stats, atomics-free hist via LDS label scan
//  bid >= 256 : y prep (2 pairs x 1024 blocks x 4 rows)
// block 0 additionally zeroes accum + completion counter (stream-ordered vs fused/merge).
__global__ void prep_kernel(const float* __restrict__ yimg, const float* __restrict__ ytxt,
                            const float* __restrict__ cw, const int* __restrict__ labels,
                            char* __restrict__ ws, double* __restrict__ accum,
                            int* __restrict__ cnt) {
    const int bid = blockIdx.x;
    const int tid = threadIdx.x;
    const int t = tid & 63;
    if (bid < 256) {
        __shared__ int labL[4096];
        #pragma unroll
        for (int i = 0; i < 4; ++i)
            ((int4*)labL)[tid + i * 256] = ((const int4*)labels)[tid + i * 256];
        if (bid == 0 && tid == 0) { accum[0] = 0.0; accum[1] = 0.0; *cnt = 0; }
        __syncthreads();
        int c = bid * 4 + (tid >> 6);
        int srcc = (c < 1000) ? c : 0;             // pad rows reuse class 0 (weight 0)
        float4 v = ((const float4*)(cw + (size_t)srcc * DD))[t];
        ushort4 h;
        h.x = f2bf(v.x); h.y = f2bf(v.y); h.z = f2bf(v.z); h.w = f2bf(v.w);
        ((ushort4*)(ws + AHI_B + (size_t)c * 512))[t] = h;
        float sq = v.x*v.x + v.y*v.y + v.z*v.z + v.w*v.w;
        #pragma unroll
        for (int off = 32; off > 0; off >>= 1) sq += __shfl_down(sq, off);
        // atomics-free class count: 64 lanes scan 64 labels each
        int cn = 0;
        #pragma unroll 8
        for (int i = t; i < 4096; i += 64) cn += (labL[i] == c) ? 1 : 0;
        #pragma unroll
        for (int off = 32; off > 0; off >>= 1) cn += __shfl_down(cn, off);
        if (t == 0) {
            float xn = sqrtf(sq);
            float invxn = 1.0f / xn;
            float a = 0.1f * (1.f - sq) * invxn;
            a = fminf(fmaxf(a, -CLIPV), CLIPV);
            float psi = asinf(a);
            ((float4*)(ws + RS0_B))[c] = make_float4(sq, xn, invxn + xn, psi);
            ((float*)(ws + CNTF_B))[c] = (float)cn;
        }
    } else {
        int k = bid - 256;                         // 0..2047
        int pair = k >> 10;
        int row = (k & 1023) * 4 + (tid >> 6);
        const float* Y = pair ? ytxt : yimg;
        float4 v = ((const float4*)(Y + (size_t)row * DD))[t];
        ushort4 h;
        h.x = f2bf(v.x); h.y = f2bf(v.y); h.z = f2bf(v.z); h.w = f2bf(v.w);
        ((ushort4*)(ws + YHI_B + (size_t)pair * 2097152 + (size_t)row * 512))[t] = h;
        float sq = v.x*v.x + v.y*v.y + v.z*v.z + v.w*v.w;
        #pragma unroll
        for (int off = 32; off > 0; off >>= 1) sq += __shfl_down(sq, off);
        if (t == 0)
            ((float2*)(ws + YS_B))[(size_t)pair * BB + row] = make_float2(sq, __int_as_float(labels[row]));
    }
}

// 128x128 tile over [class(1024) x y(4096)], 512 threads (8 waves, 4x2),
// K-chunk 64 double-buffered, k-group-major LDS, packed-f32 elementwise,
// DPP reductions, class-multiplicity weights. NO fences, NO in-kernel merge
// (R11 lesson: per-wave device fences cost ~80 us across the grid).
__launch_bounds__(512, 3)
__global__ void fused_kernel(char* __restrict__ ws, double* __restrict__ accum) {
    __shared__ unsigned short AhL[2][8192], BhL[2][8192];  // 16 KB per buf
    __shared__ float4 rs0l[128];
    __shared__ float2 ysl[128];
    __shared__ float  cntl[128];
    __shared__ float  smrg[128][8];
    __shared__ float  sAtom[8];

    const int tid = threadIdx.x;
    const int l = tid & 63;
    const int w = tid >> 6;                 // 0..7
    const int wm = w >> 1, wn = w & 1;      // 4x2 wave grid; 32x64 per wave
    const int bx = blockIdx.x, by = blockIdx.y, pair = blockIdx.z;
    const int rowbase = by * 128, colbase = bx * 128;

    const char* srcA = ws + AHI_B + ((size_t)(rowbase + (w & 1) * 64 + l)) * 512 + (w >> 1) * 16;
    const char* srcB = ws + YHI_B + (size_t)pair * 2097152
                     + ((size_t)(colbase + (w & 1) * 64 + l)) * 512 + (w >> 1) * 16;
    const unsigned wboff = (unsigned)((w >> 1) * 2048 + (w & 1) * 1024);  // wave-uniform

    if (tid < 128) {
        rs0l[tid] = ((const float4*)(ws + RS0_B))[rowbase + tid];
    } else if (tid < 256) {
        ysl[tid - 128] = ((const float2*)(ws + YS_B))[(size_t)pair * BB + (tid - 128) + colbase];
    } else if (tid < 384) {
        cntl[tid - 256] = ((const float*)(ws + CNTF_B))[rowbase + (tid - 256)];
    }

    f32x4 acc[2][4];
    #pragma unroll
    for (int i = 0; i < 2; ++i)
        #pragma unroll
        for (int j = 0; j < 4; ++j) acc[i][j] = (f32x4){0.f, 0.f, 0.f, 0.f};

    // ---- prologue: stage chunk 0 into buf 0 ----
    gload16(srcA,      (char*)AhL[0] + wboff);
    gload16(srcA + 64, (char*)AhL[0] + wboff + 8192);
    gload16(srcB,      (char*)BhL[0] + wboff);
    gload16(srcB + 64, (char*)BhL[0] + wboff + 8192);
    asm volatile("s_waitcnt vmcnt(0)" ::: "memory");
    __syncthreads();

    #pragma unroll
    for (int c = 0; c < 4; ++c) {
        const int nb = (c + 1) & 1, cb = c & 1;
        if (c < 3) {                               // prefetch next chunk (overlaps MFMA)
            gload16(srcA + (c + 1) * 128,      (char*)AhL[nb] + wboff);
            gload16(srcA + (c + 1) * 128 + 64, (char*)AhL[nb] + wboff + 8192);
            gload16(srcB + (c + 1) * 128,      (char*)BhL[nb] + wboff);
            gload16(srcB + (c + 1) * 128 + 64, (char*)BhL[nb] + wboff + 8192);
        }
        #pragma unroll
        for (int ks = 0; ks < 2; ++ks) {
            const int kgl = ks * 4 + (l >> 4);
            const int abyte = (kgl * 128 + wm * 32 + (l & 15)) * 16;
            const int bbyte = (kgl * 128 + wn * 64 + (l & 15)) * 16;
            bf16x8 ah[2], bh[4];
            #pragma unroll
            for (int mi = 0; mi < 2; ++mi)
                ah[mi] = *(const bf16x8*)((const char*)AhL[cb] + abyte + mi * 256);
            #pragma unroll
            for (int ni = 0; ni < 4; ++ni)
                bh[ni] = *(const bf16x8*)((const char*)BhL[cb] + bbyte + ni * 256);
            #pragma unroll
            for (int mi = 0; mi < 2; ++mi)
                #pragma unroll
                for (int ni = 0; ni < 4; ++ni)
                    acc[mi][ni] = __builtin_amdgcn_mfma_f32_16x16x32_bf16(ah[mi], bh[ni], acc[mi][ni], 0, 0, 0);
        }
        if (c < 3) {
            asm volatile("s_waitcnt vmcnt(0)" ::: "memory");
            __syncthreads();
        }
    }

    // ---- elementwise (packed f32 pairs over ni), class rows weighted by cnt ----
    f32x2 entl2 = splat2(0.f);
    f32x2 y2p[2], opy2p[2];
    int labyc[4];
    #pragma unroll
    for (int p = 0; p < 2; ++p) {
        float2 a = ysl[wn * 64 + (p * 2 + 0) * 16 + (l & 15)];
        float2 b = ysl[wn * 64 + (p * 2 + 1) * 16 + (l & 15)];
        y2p[p] = (f32x2){a.x, b.x};
        opy2p[p] = (f32x2){1.f + a.x, 1.f + b.x};
        labyc[p * 2 + 0] = __float_as_int(a.y);
        labyc[p * 2 + 1] = __float_as_int(b.y);
    }
    #pragma unroll
    for (int mi = 0; mi < 2; ++mi) {
        #pragma unroll
        for (int rr = 0; rr < 4; ++rr) {
            int rl_ = wm * 32 + mi * 16 + (l >> 4) * 4 + rr;
            int cls = rowbase + rl_;
            float4 r0 = rs0l[rl_];
            float cntw = cntl[rl_];
            float x2 = r0.x, xn = r0.y, opx2i = r0.z, psi = r0.w;
            f32x2 x2py2[2], x2y2p1[2], xnopy2[2];
            #pragma unroll
            for (int p = 0; p < 2; ++p) {
                x2py2[p]  = y2p[p] + x2;
                x2y2p1[p] = y2p[p] * x2 + 1.f;
                xnopy2[p] = opy2p[p] * xn;
            }
            f32x2 S2 = splat2(0.f), T2 = splat2(0.f), PP2 = splat2(0.f), rowE = splat2(0.f);
            #pragma unroll
            for (int p = 0; p < 2; ++p) {
                bool pos0 = (cls == labyc[p * 2 + 0]);
                bool pos1 = (cls == labyc[p * 2 + 1]);
                f32x2 dotv = (f32x2){acc[mi][p * 2 + 0][rr], acc[mi][p * 2 + 1][rr]};
                f32x2 m2dot = dotv * -2.f;
                f32x2 d2 = x2py2[p] + m2dot;                    // ||x-y||^2
                f32x2 q2 = x2y2p1[p] + m2dot;                   // mobius denom
                f32x2 t = emax2(d2 * q2, splat2(1e-30f));
                f32x2 rs = (f32x2){__builtin_amdgcn_rsqf(t[0]), __builtin_amdgcn_rsqf(t[1])};
                f32x2 s_ = t * rs;                              // sqrt(q2*d2)
                // --- entailment E ---
                f32x2 numer = dotv * opx2i - xnopy2[p];
                f32x2 arg = numer * rs;
                f32x2 ax = emin2(__builtin_elementwise_abs(arg), splat2(CLIPV));
                f32x2 pl = ax * -0.0012624911f + 0.0066700901f;
                pl = pl * ax + -0.0170881256f;
                pl = pl * ax +  0.0308918810f;
                pl = pl * ax + -0.0501743046f;
                pl = pl * ax +  0.0889789874f;
                pl = pl * ax + -0.2145988016f;
                pl = pl * ax +  1.5707963050f;
                f32x2 om = 1.f - ax;
                f32x2 sq = (f32x2){sqrtf(om[0]), sqrtf(om[1])};
                f32x2 racos = sq * pl;
                f32x2 pmr = PIF - racos;
                f32x2 theta;
                theta[0] = (arg[0] < 0.f) ? pmr[0] : racos[0];
                theta[1] = (arg[1] < 0.f) ? pmr[1] : racos[1];
                f32x2 h = theta - psi;
                f32x2 g = emax2(h, splat2(0.f));
                f32x2 nc = emax2(1.f - g, splat2(0.f));
                f32x2 contrib;
                contrib[0] = pos0 ? g[0] : nc[0];
                contrib[1] = pos1 ? g[1] : nc[1];
                rowE += contrib;
                // --- dist + softmax: e = exp(-dist) = (q2e-s)/(q2e+s) ---
                f32x2 q2e = q2 + 1e-5f;
                f32x2 ne = q2e - s_;
                f32x2 de = q2e + s_;
                f32x2 rd = (f32x2){__builtin_amdgcn_rcpf(de[0]), __builtin_amdgcn_rcpf(de[1])};
                f32x2 e_ = ne * rd;
                f32x2 lu = (f32x2){__builtin_amdgcn_logf(e_[0]), __builtin_amdgcn_logf(e_[1])};
                f32x2 nd = lu * LN2F;                           // -dist
                S2 += e_;
                T2 = e_ * nd + T2;
                f32x2 pe;
                pe[0] = pos0 ? e_[0] : 0.f;
                pe[1] = pos1 ? e_[1] : 0.f;
                PP2 += pe;
            }
            entl2 = rowE * splat2(cntw) + entl2;    // weight by class multiplicity
            float S = rowsum16(S2[0] + S2[1]);
            float T = rowsum16(T2[0] + T2[1]);
            float PP = rowsum16(PP2[0] + PP2[1]);
            if ((l & 15) == 0) {
                smrg[rl_][wn * 4 + 0] = S; smrg[rl_][wn * 4 + 1] = T; smrg[rl_][wn * 4 + 2] = PP;
            }
        }
    }
    __syncthreads();
    if (tid < 128) {
        float4 o;
        o.x = smrg[tid][0] + smrg[tid][4];
        o.y = smrg[tid][1] + smrg[tid][5];
        o.z = smrg[tid][2] + smrg[tid][6];
        o.w = 0.f;
        ((float4*)(ws + PART_B))[((size_t)pair * 32 + bx) * CC + rowbase + tid] = o;
    }
    float entl = entl2[0] + entl2[1];
    #pragma unroll
    for (int off = 32; off > 0; off >>= 1) entl += __shfl_xor(entl, off);
    if (l == 0) sAtom[w] = entl;
    __syncthreads();
    if (tid == 0) {
        float tot = 0.f;
        #pragma unroll
        for (int i = 0; i < 8; ++i) tot += sAtom[i];
        atomicAdd(&accum[0], (double)tot);
    }
}

// merge + finalize (last of 8 blocks writes out; tid0-only fence — cheap)
__global__ void merge_kernel(const char* __restrict__ ws, double* __restrict__ accum,
                             int* __restrict__ cnt, float* __restrict__ out) {
    __shared__ double sbuf[4];
    int idx = blockIdx.x * 256 + threadIdx.x;     // 0..2047
    int pair = idx >> 10, c = idx & 1023;
    const float4* part = (const float4*)(ws + PART_B) + (size_t)pair * 32 * CC + c;
    float S = 0.f, T = 0.f, PP = 0.f;
    #pragma unroll 4
    for (int cb = 0; cb < 32; ++cb) {
        float4 v = part[(size_t)cb * CC];
        S += v.x; T += v.y; PP += v.z;
    }
    float wgt = ((const float*)(ws + CNTF_B))[c];
    float logc = logf(1.0f / wgt + 1e-5f);        // inf for wgt==0, guarded below
    float invS = 1.f / S;
    float fp = PP * invS;
    float rl = T * invS - logf(S) - fp * logc - (1.f - fp) * LOG_EPS_C;
    double dv = (wgt > 0.f) ? (double)(rl * wgt) : 0.0;
    #pragma unroll
    for (int off = 32; off > 0; off >>= 1) dv += __shfl_down(dv, off);
    int lane = threadIdx.x & 63, wv = threadIdx.x >> 6;
    if (lane == 0) sbuf[wv] = dv;
    __syncthreads();
    if (threadIdx.x == 0) {
        atomicAdd(&accum[1], sbuf[0] + sbuf[1] + sbuf[2] + sbuf[3]);
        __threadfence();
        int old = atomicAdd(cnt, 1);
        if (old == (int)gridDim.x - 1) {           // last block: finalize
            __threadfence();
            float e = (float)accum[0];
            float h = (float)(accum[1] * (1.0 / 4096.0));
            out[0] = e;
            out[1] = h;
            out[2] = e + h;
        }
    }
}

extern "C" void kernel_launch(void* const* d_in, const int* in_sizes, int n_in,
                              void* d_out, int out_size, void* d_ws, size_t ws_size,
                              hipStream_t stream) {
    (void)in_sizes; (void)n_in; (void)out_size; (void)ws_size;
    const float* img = (const float*)d_in[0];
    const float* txt = (const float*)d_in[1];
    const float* cw  = (const float*)d_in[2];
    const int* labels = (const int*)d_in[3];
    float* out = (float*)d_out;
    char* wsb = (char*)d_ws;
    double* accum = (double*)(wsb + ACC_B);
    int* cnt = (int*)(wsb + CNT_B);

    prep_kernel<<<2304, 256, 0, stream>>>(img, txt, cw, labels, wsb, accum, cnt);
    fused_kernel<<<dim3(32, 8, 2), 512, 0, stream>>>(wsb, accum);
    merge_kernel<<<8, 256, 0, stream>>>(wsb, accum, cnt, out);
}